// Round 7
// baseline (1084.081 us; speedup 1.0000x reference)
//
#include <hip/hip_runtime.h>
#include <hip/hip_bf16.h>
#include <stdint.h>

#define T_TOK 1024
#define H_DIM 2048
#define NEXP 8
#define IED 1408
#define ISD 5632

typedef __attribute__((ext_vector_type(8))) short s16x8;
typedef __attribute__((ext_vector_type(8))) unsigned short u16x8;
typedef __attribute__((ext_vector_type(4))) float f32x4;

// A-tile chunk swizzle (bank-quad balanced, period 16 rows)
#define SWZ(r) (((r) ^ ((r) >> 2)) & 3)
// B LDS row stride in shorts (72 B): pad => balanced banks for write & read
#define BSTR 36
#define A_OFF(i) ((i) * 4096)
#define B_OFF(i) ((i) * 4608)

// HW bf16 convert (RNE; lowers to v_cvt_pk_bf16_f32 on gfx950)
__device__ __forceinline__ unsigned short f2bf(float f) {
  union { __hip_bfloat16 b; unsigned short u; } v;
  v.b = __float2bfloat16(f);
  return v.u;
}

__device__ __forceinline__ void gload16(const void* g, void* l) {
  __builtin_amdgcn_global_load_lds(
      (const __attribute__((address_space(1))) unsigned int*)g,
      (__attribute__((address_space(3))) unsigned int*)l, 16, 0, 0);
}

// ---------------- router + x->bf16 convert (fused) ----------------
extern "C" __global__ void __launch_bounds__(256) k_router(
    const float* __restrict__ x, const float* __restrict__ wg,
    const float* __restrict__ wsg, unsigned short* __restrict__ xb,
    int* __restrict__ counts, int* __restrict__ tlist,
    float* __restrict__ wlist, float* __restrict__ gate_sig) {
  const int tid = threadIdx.x;
  const int bb = blockIdx.x;
#pragma unroll
  for (int it = 0; it < 8; it++) {
    int i = bb * 8192 + it * 1024 + tid * 4;
    float4 v = *(const float4*)(x + i);
    ushort4 o;
    o.x = f2bf(v.x); o.y = f2bf(v.y); o.z = f2bf(v.z); o.w = f2bf(v.w);
    *(ushort4*)(xb + i) = o;
  }
  const int lane = tid & 63;
  const int t = bb * 4 + (tid >> 6);
  const float* xr = x + (size_t)t * H_DIM;
  float acc[8];
#pragma unroll
  for (int e = 0; e < 8; e++) acc[e] = 0.f;
  float sg = 0.f;
  for (int h = lane; h < H_DIM; h += 64) {
    float xv = xr[h];
    float4 w0 = *(const float4*)(wg + h * 8);
    float4 w1 = *(const float4*)(wg + h * 8 + 4);
    acc[0] += xv * w0.x; acc[1] += xv * w0.y; acc[2] += xv * w0.z; acc[3] += xv * w0.w;
    acc[4] += xv * w1.x; acc[5] += xv * w1.y; acc[6] += xv * w1.z; acc[7] += xv * w1.w;
    sg += xv * wsg[h];
  }
#pragma unroll
  for (int d = 32; d >= 1; d >>= 1) {
#pragma unroll
    for (int e = 0; e < 8; e++) acc[e] += __shfl_xor(acc[e], d, 64);
    sg += __shfl_xor(sg, d, 64);
  }
  if (lane == 0) {
    float m = acc[0];
#pragma unroll
    for (int e = 1; e < 8; e++) m = fmaxf(m, acc[e]);
    float p[8], s = 0.f;
#pragma unroll
    for (int e = 0; e < 8; e++) { p[e] = __expf(acc[e] - m); s += p[e]; }
    float inv = 1.f / s;
    bool used[8];
#pragma unroll
    for (int e = 0; e < 8; e++) used[e] = false;
    for (int j = 0; j < 4; j++) {
      int be = 0; float bv = -1e30f;
#pragma unroll
      for (int e = 0; e < 8; e++)
        if (!used[e] && acc[e] > bv) { bv = acc[e]; be = e; }
      used[be] = true;
      int slot = atomicAdd(counts + be, 1);
      tlist[be * T_TOK + slot] = t;
      wlist[be * T_TOK + slot] = p[be] * inv;
    }
    gate_sig[t] = 1.f / (1.f + __expf(-sg));
  }
}

// ---------------- staging / compute macros (BK=32, 3-stage) ----------------
#define ISSUE_A(kk, AOFF)                                                 \
  do {                                                                    \
    _Pragma("unroll") for (int q = 0; q < 2; q++)                         \
        gload16(asrc[q] + (kk), adst[q] + (AOFF));                        \
    __builtin_amdgcn_sched_barrier(0);                                    \
  } while (0)

#define ISSUE_B(SET, kk)                                                  \
  do {                                                                    \
    _Pragma("unroll") for (int i = 0; i < 8; i++)                         \
        SET[i] = *(const float2*)(Bh + (size_t)((kk) + bks + i) * (size_t)ldb + bn); \
    __builtin_amdgcn_sched_barrier(0);                                    \
  } while (0)

#define CVTB(SET, BOFF)                                                   \
  do {                                                                    \
    _Pragma("unroll") for (int jj = 0; jj < 2; jj++) {                    \
      u16x8 pk;                                                           \
      _Pragma("unroll") for (int i = 0; i < 8; i++)                       \
          pk[i] = f2bf(jj ? SET[i].y : SET[i].x);                         \
      *(u16x8*)(bwr[jj] + (BOFF)) = pk;                                   \
    }                                                                     \
  } while (0)

#define COMPUTE(AOFF, BOFF)                                               \
  do {                                                                    \
    const unsigned short* ab = a_lds + (AOFF);                            \
    const unsigned short* bb2 = b_lds + (BOFF);                           \
    __builtin_amdgcn_s_setprio(1);                                        \
    {                                                                     \
      const int kc = lane >> 4;                                           \
      s16x8 afr[4];                                                       \
      _Pragma("unroll") for (int m = 0; m < 4; m++) {                     \
        int r = wm * 64 + m * 16 + (lane & 15);                           \
        afr[m] = *(const s16x8*)&ab[r * 32 + ((kc ^ SWZ(r)) * 8)];        \
      }                                                                   \
      _Pragma("unroll") for (int nf = 0; nf < 4; nf++) {                  \
        int rb_;                                                          \
        if constexpr (DOWN) rb_ = wn * 64 + nf * 16;                      \
        else rb_ = wn * 32 + (nf & 1) * 16 + (nf >> 1) * 64;              \
        rb_ += (lane & 15);                                               \
        s16x8 bfr = *(const s16x8*)&bb2[rb_ * BSTR + kc * 8];             \
        _Pragma("unroll") for (int m = 0; m < 4; m++)                     \
            acc[m][nf] = __builtin_amdgcn_mfma_f32_16x16x32_bf16(         \
                afr[m], bfr, acc[m][nf], 0, 0, 0);                        \
      }                                                                   \
    }                                                                     \
    __builtin_amdgcn_s_setprio(0);                                        \
  } while (0)

// One pipeline step. Ledger at the end-of-step barrier (steady state):
// in-flight = A(u+2)[2] + B(u+2)[8] + B(u+3)[8] = 18; waiting vmcnt(18)
// drains A(u+1) (older than all 18, issue order pinned A-before-B).
#define STEP(UU, S0, S1, S2, I0, I1, I2)                                  \
  do {                                                                    \
    const int u_ = (UU);                                                  \
    if (u_ + 2 < nt) ISSUE_A(kbeg + (u_ + 2) * 32, A_OFF(I2));            \
    if (u_ + 3 < nt) ISSUE_B(S0, kbeg + (u_ + 3) * 32);                   \
    if (u_ + 1 < nt) CVTB(S1, B_OFF(I1));                                 \
    COMPUTE(A_OFF(I0), B_OFF(I0));                                        \
    if (u_ + 1 < nt) {                                                    \
      __builtin_amdgcn_sched_barrier(0);                                  \
      if (u_ + 3 < nt)                                                    \
        asm volatile("s_waitcnt vmcnt(18)" ::: "memory");                 \
      else if (u_ + 2 < nt)                                               \
        asm volatile("s_waitcnt vmcnt(10)" ::: "memory");                 \
      else                                                                \
        asm volatile("s_waitcnt vmcnt(0)" ::: "memory");                  \
      asm volatile("s_waitcnt lgkmcnt(0)" ::: "memory");                  \
      __builtin_amdgcn_s_barrier();                                       \
      __builtin_amdgcn_sched_barrier(0);                                  \
    }                                                                     \
  } while (0)

// ---------------- fused MFMA GEMM pair, 3-stage pipeline, XCD-grouped ----------------
// DOWN=0: shared-gu (blocks 0..703) + expert-gu (704..2111), K=2048 (nt=64)
// DOWN=1: shared-down splitK4 (0..511) + expert-down (512..1535), K=1408 (nt=44)
template <int DOWN>
__global__ void __launch_bounds__(256, 3) k_mm(
    const unsigned short* __restrict__ A_sh, const unsigned short* __restrict__ A_ex,
    const float* __restrict__ B_sh, const float* __restrict__ B_ex,
    unsigned short* __restrict__ act_sh, unsigned short* __restrict__ act_ex,
    float* __restrict__ out,
    const int* __restrict__ counts, const int* __restrict__ tlist,
    const float* __restrict__ wlist, const float* __restrict__ gate_sig) {
  const int tid = threadIdx.x;
  const int lane = tid & 63;
  const int wid = tid >> 6;
  const int wm = wid >> 1, wn = wid & 1;

  constexpr int SHBLK = DOWN ? 512 : 704;
  const int b0 = blockIdx.x;
  const bool ex = b0 >= SHBLK;
  const int b = ex ? b0 - SHBLK : b0;
  const int xcd = b & 7;
  const int j = b >> 3;
  const int mtile = j & 7;
  int e = 0, ntile = 0, z = 0;
  if constexpr (!DOWN) {
    if (!ex) ntile = xcd * 11 + (j >> 3);
    else { int p = xcd * 22 + (j >> 3); e = p & 7; ntile = p >> 3; }
  } else {
    if (!ex) { int p = xcd * 8 + (j >> 3); ntile = p >> 2; z = p & 3; }
    else { int p = xcd * 16 + (j >> 3); e = p & 7; ntile = p >> 3; }
  }

  int lda, ldb, IK = 0, kbeg = 0, count = T_TOK;
  const unsigned short* A;
  const float* B0; const float* B1;
  const int* tlA = nullptr;   // A-row gather (gu-expert ONLY)
  const int* tlO = nullptr;   // output token scatter (down-expert ONLY)
  const float* wl = nullptr;
  unsigned short* actout = nullptr;

  if constexpr (!DOWN) {
    lda = H_DIM;
    if (!ex) {
      ldb = 2 * ISD; IK = ISD; A = A_sh; actout = act_sh;
      B0 = B_sh + ntile * 64; B1 = B_sh + ISD + ntile * 64;
    } else {
      count = counts[e];
      if (mtile * 128 >= count) return;
      ldb = 2 * IED; IK = IED; A = A_sh;
      const float* Bw = B_ex + (size_t)e * H_DIM * (2 * IED);
      B0 = Bw + ntile * 64; B1 = Bw + IED + ntile * 64;
      tlA = tlist + e * T_TOK; wl = wlist + e * T_TOK;
      actout = act_ex + (size_t)e * T_TOK * IED;
    }
  } else {
    ldb = H_DIM;
    if (!ex) {
      lda = ISD; kbeg = z * 1408; A = A_sh;
      B0 = B_sh + ntile * 128; B1 = B0 + 64;
    } else {
      count = counts[e];
      if (mtile * 128 >= count) return;
      lda = IED; A = A_ex + (size_t)e * T_TOK * IED;  // rows indexed by SLOT
      B0 = B_ex + (size_t)e * IED * H_DIM + ntile * 128; B1 = B0 + 64;
      tlO = tlist + e * T_TOK;
    }
  }
  const int nt = DOWN ? 44 : 64;

  __shared__ unsigned short a_lds[3 * 4096];  // 3 bufs x [128 rows][4 chunks of 8]
  __shared__ unsigned short b_lds[3 * 4608];  // 3 bufs x [128 rows][BSTR=36] (padded)

  // A: global_load_lds, pre-swizzled source chunk, linear LDS dest.
  const unsigned short* asrc[2];
  unsigned short* adst[2];
#pragma unroll
  for (int q = 0; q < 2; q++) {
    int row = wid * 32 + q * 16 + (lane >> 2);
    int rowg = mtile * 128 + row;
    int arow = rowg;
    if (tlA) arow = tlA[rowg];  // padding slots hold 0 (memset)
    asrc[q] = A + (size_t)arow * lda + (((lane & 3) ^ SWZ(row)) * 8);
    adst[q] = &a_lds[(wid * 32 + q * 16) * 32];
  }

  // B staging: half = tid>>7; 2 cols bn,bn+1; k-chunk kg. Padded rows, no swizzle.
  const int half = tid >> 7;
  const int bn = (tid & 31) * 2;
  const int kg = (tid >> 5) & 3;
  const int bks = kg * 8;
  const float* Bh = half ? B1 : B0;
  unsigned short* bwr[2];
#pragma unroll
  for (int jj = 0; jj < 2; jj++) {
    int r = half * 64 + bn + jj;
    bwr[jj] = &b_lds[r * BSTR + kg * 8];
  }

  const f32x4 fzero = {0.f, 0.f, 0.f, 0.f};
  f32x4 acc[4][4];
#pragma unroll
  for (int m = 0; m < 4; m++)
#pragma unroll
    for (int n = 0; n < 4; n++) acc[m][n] = fzero;

  float2 RB0[8], RB1[8], RB2[8];

  // ---- prologue: establish steady-state invariant ----
  ISSUE_A(kbeg, A_OFF(0));            // A(0)
  ISSUE_B(RB0, kbeg);                 // B(0)
  ISSUE_A(kbeg + 32, A_OFF(1));       // A(1)
  ISSUE_B(RB1, kbeg + 32);            // B(1)
  CVTB(RB0, B_OFF(0));                // waits B(0) (also drains A(0), older)
  ISSUE_B(RB2, kbeg + 64);            // B(2)
  __builtin_amdgcn_sched_barrier(0);
  asm volatile("s_waitcnt lgkmcnt(0)" ::: "memory");
  __builtin_amdgcn_s_barrier();
  __builtin_amdgcn_sched_barrier(0);
  // entry state: in-flight A(1)[2], B(1)[8], B(2)[8]

  for (int u = 0; u < nt; u += 3) {
    STEP(u,     RB0, RB1, RB2, 0, 1, 2);
    if (u + 1 < nt) STEP(u + 1, RB1, RB2, RB0, 1, 2, 0);
    if (u + 2 < nt) STEP(u + 2, RB2, RB0, RB1, 2, 0, 1);
  }

  if constexpr (!DOWN) {
#pragma unroll
    for (int m = 0; m < 4; m++) {
#pragma unroll
      for (int i = 0; i < 4; i++) {
        int rowslot = mtile * 128 + wm * 64 + m * 16 + (lane >> 4) * 4 + i;
        float rsc = 1.f;
        if (wl) rsc = wl[rowslot];  // padding slots: 0.0 (memset)
#pragma unroll
        for (int p = 0; p < 2; p++) {
          float g = acc[m][p][i];
          float u2 = acc[m][p + 2][i];
          float sv = g / (1.f + __expf(-g)) * u2 * rsc;
          int col = ntile * 64 + wn * 32 + p * 16 + (lane & 15);
          actout[(size_t)rowslot * IK + col] = f2bf(sv);
        }
      }
    }
  } else {
#pragma unroll
    for (int m = 0; m < 4; m++) {
#pragma unroll
      for (int i = 0; i < 4; i++) {
        int rowslot = mtile * 128 + wm * 64 + m * 16 + (lane >> 4) * 4 + i;
        int token = rowslot;
        if (tlO) token = tlO[rowslot];  // padding: token 0, acc==0
        float sc = ex ? 1.f : gate_sig[token];
        float* orow = out + (size_t)token * H_DIM + ntile * 128 + wn * 64 + (lane & 15);
#pragma unroll
        for (int nf = 0; nf < 4; nf++)
          atomicAdd(orow + nf * 16, acc[m][nf][i] * sc);
      }
    }
  }
}

extern "C" void kernel_launch(void* const* d_in, const int* in_sizes, int n_in,
                              void* d_out, int out_size, void* d_ws, size_t ws_size,
                              hipStream_t stream) {
  (void)in_sizes; (void)n_in; (void)out_size; (void)ws_size;
  const float* x    = (const float*)d_in[0];
  const float* wg   = (const float*)d_in[1];
  const float* wsg  = (const float*)d_in[2];
  const float* wsgu = (const float*)d_in[3];
  const float* wsd  = (const float*)d_in[4];
  const float* wegu = (const float*)d_in[5];
  const float* wed  = (const float*)d_in[6];
  float* out = (float*)d_out;

  char* ws = (char*)d_ws;
  unsigned short* xb   = (unsigned short*)ws;                                   // 4 MB
  unsigned short* acts = (unsigned short*)(ws + (4u << 20));                    // T*ISD bf16
  unsigned short* acte = (unsigned short*)(ws + (4u << 20) + 11534336u);        // E*T*IED bf16
  char* ctrl = ws + (4u << 20) + 11534336u + 23068672u;
  int* counts    = (int*)ctrl;
  int* tlist     = (int*)(ctrl + 256);
  float* wlist   = (float*)(ctrl + 256 + 32768);
  float* gate_sig = (float*)(ctrl + 256 + 65536);

  hipMemsetAsync(d_out, 0, (size_t)T_TOK * H_DIM * 4, stream);
  hipMemsetAsync(ctrl, 0, 256 + 65536, stream);

  k_router<<<dim3(256), dim3(256), 0, stream>>>(x, wg, wsg, xb, counts, tlist, wlist, gate_sig);
  k_mm<0><<<dim3(2112), dim3(256), 0, stream>>>(xb, xb, wsgu, wegu, acts, acte, nullptr,
                                                counts, tlist, wlist, gate_sig);
  k_mm<1><<<dim3(1536), dim3(256), 0, stream>>>(acts, acte, wsd, wed, nullptr, nullptr, out,
                                                counts, tlist, wlist, gate_sig);
}

// Round 8
// 901.373 us; speedup vs baseline: 1.2027x; 1.2027x over previous
//
#include <hip/hip_runtime.h>
#include <hip/hip_bf16.h>
#include <stdint.h>

#define T_TOK 1024
#define H_DIM 2048
#define NEXP 8
#define IED 1408
#define ISD 5632

typedef __attribute__((ext_vector_type(8))) short s16x8;
typedef __attribute__((ext_vector_type(8))) unsigned short u16x8;
typedef __attribute__((ext_vector_type(4))) float f32x4;

// chunk swizzle (bank-quad balanced, period 16 rows)
#define SWZ(r) (((r) ^ ((r) >> 2)) & 3)
// B LDS row permutation: mixes row parity within each write instruction
#define PERM(n) ((((n) & 63) >> 1) + (((n) & 1) << 5) + ((n) & 64))

// HW bf16 convert (RNE, lowers to v_cvt_pk_bf16_f32)
__device__ __forceinline__ unsigned short f2bf(float f) {
  union { __hip_bfloat16 b; unsigned short u; } v;
  v.b = __float2bfloat16(f);
  return v.u;
}

__device__ __forceinline__ void gload16(const void* g, void* l) {
  __builtin_amdgcn_global_load_lds(
      (const __attribute__((address_space(1))) unsigned int*)g,
      (__attribute__((address_space(3))) unsigned int*)l, 16, 0, 0);
}

// ---------------- router + x->bf16 convert (fused) ----------------
extern "C" __global__ void __launch_bounds__(256) k_router(
    const float* __restrict__ x, const float* __restrict__ wg,
    const float* __restrict__ wsg, unsigned short* __restrict__ xb,
    int* __restrict__ counts, int* __restrict__ tlist,
    float* __restrict__ wlist, float* __restrict__ gate_sig) {
  const int tid = threadIdx.x;
  const int bb = blockIdx.x;
#pragma unroll
  for (int it = 0; it < 8; it++) {
    int i = bb * 8192 + it * 1024 + tid * 4;
    float4 v = *(const float4*)(x + i);
    ushort4 o;
    o.x = f2bf(v.x); o.y = f2bf(v.y); o.z = f2bf(v.z); o.w = f2bf(v.w);
    *(ushort4*)(xb + i) = o;
  }
  const int lane = tid & 63;
  const int t = bb * 4 + (tid >> 6);
  const float* xr = x + (size_t)t * H_DIM;
  float acc[8];
#pragma unroll
  for (int e = 0; e < 8; e++) acc[e] = 0.f;
  float sg = 0.f;
  for (int h = lane; h < H_DIM; h += 64) {
    float xv = xr[h];
    float4 w0 = *(const float4*)(wg + h * 8);
    float4 w1 = *(const float4*)(wg + h * 8 + 4);
    acc[0] += xv * w0.x; acc[1] += xv * w0.y; acc[2] += xv * w0.z; acc[3] += xv * w0.w;
    acc[4] += xv * w1.x; acc[5] += xv * w1.y; acc[6] += xv * w1.z; acc[7] += xv * w1.w;
    sg += xv * wsg[h];
  }
#pragma unroll
  for (int d = 32; d >= 1; d >>= 1) {
#pragma unroll
    for (int e = 0; e < 8; e++) acc[e] += __shfl_xor(acc[e], d, 64);
    sg += __shfl_xor(sg, d, 64);
  }
  if (lane == 0) {
    float m = acc[0];
#pragma unroll
    for (int e = 1; e < 8; e++) m = fmaxf(m, acc[e]);
    float p[8], s = 0.f;
#pragma unroll
    for (int e = 0; e < 8; e++) { p[e] = __expf(acc[e] - m); s += p[e]; }
    float inv = 1.f / s;
    bool used[8];
#pragma unroll
    for (int e = 0; e < 8; e++) used[e] = false;
    for (int j = 0; j < 4; j++) {
      int be = 0; float bv = -1e30f;
#pragma unroll
      for (int e = 0; e < 8; e++)
        if (!used[e] && acc[e] > bv) { bv = acc[e]; be = e; }
      used[be] = true;
      int slot = atomicAdd(counts + be, 1);
      tlist[be * T_TOK + slot] = t;
      wlist[be * T_TOK + slot] = p[be] * inv;
    }
    gate_sig[t] = 1.f / (1.f + __expf(-sg));
  }
}

// ---------------- staging / compute macros (BK=32) ----------------
#define ISSUE_A(kk, AOFF)                                                 \
  do {                                                                    \
    _Pragma("unroll") for (int q = 0; q < 2; q++)                         \
        gload16(asrc[q] + (kk), adst[q] + (AOFF));                        \
    __builtin_amdgcn_sched_barrier(0);                                    \
  } while (0)

#define ISSUE_B(SET, kk)                                                  \
  do {                                                                    \
    _Pragma("unroll") for (int i = 0; i < 8; i++)                         \
        SET[i] = *(const float2*)(Bh + (size_t)((kk) + bks + i) * (size_t)ldb + bn); \
    __builtin_amdgcn_sched_barrier(0);                                    \
  } while (0)

#define CVTB(SET, BOFF)                                                   \
  do {                                                                    \
    _Pragma("unroll") for (int jj = 0; jj < 2; jj++) {                    \
      u16x8 pk;                                                           \
      _Pragma("unroll") for (int i = 0; i < 8; i++)                       \
          pk[i] = f2bf(jj ? SET[i].y : SET[i].x);                         \
      *(u16x8*)(bwr[jj] + (BOFF)) = pk;                                   \
    }                                                                     \
  } while (0)

#define COMPUTE(AOFF, BOFF)                                               \
  do {                                                                    \
    const unsigned short* ab = a_lds + (AOFF);                            \
    const unsigned short* bb2 = b_lds + (BOFF);                           \
    __builtin_amdgcn_s_setprio(1);                                        \
    {                                                                     \
      const int kc = lane >> 4;                                           \
      s16x8 afr[4];                                                       \
      _Pragma("unroll") for (int m = 0; m < 4; m++) {                     \
        int r = wm * 64 + m * 16 + (lane & 15);                           \
        afr[m] = *(const s16x8*)&ab[r * 32 + ((kc ^ SWZ(r)) * 8)];        \
      }                                                                   \
      _Pragma("unroll") for (int nf = 0; nf < 4; nf++) {                  \
        int rb_;                                                          \
        if constexpr (DOWN) rb_ = wn * 64 + nf * 16;                      \
        else rb_ = wn * 32 + (nf & 1) * 16 + (nf >> 1) * 64;              \
        rb_ += (lane & 15);                                               \
        int rp_ = PERM(rb_);                                              \
        s16x8 bfr = *(const s16x8*)&bb2[rp_ * 32 + ((kc ^ SWZ(rp_)) * 8)]; \
        _Pragma("unroll") for (int m = 0; m < 4; m++)                     \
            acc[m][nf] = __builtin_amdgcn_mfma_f32_16x16x32_bf16(         \
                afr[m], bfr, acc[m][nf], 0, 0, 0);                        \
      }                                                                   \
    }                                                                     \
    __builtin_amdgcn_s_setprio(0);                                        \
  } while (0)

#define PHASE_BAR(VM)                                                     \
  do {                                                                    \
    __builtin_amdgcn_sched_barrier(0);                                    \
    asm volatile("s_waitcnt vmcnt(" #VM ")" ::: "memory");                \
    asm volatile("s_waitcnt lgkmcnt(0)" ::: "memory");                    \
    __builtin_amdgcn_s_barrier();                                         \
    __builtin_amdgcn_sched_barrier(0);                                    \
  } while (0)

// Steady-state step u (uses SET holding B(u+1), refills it with B(u+3)):
//   ISSUE_A(u+2)->aF [2]; CVTB (compiler-counted wait); ISSUE_B(u+3) [8];
//   COMPUTE(aC,bC); barrier vmcnt(18) -> drains exactly A(u+1).
#define STEP_FULL(SET, K0)                                                \
  do {                                                                    \
    ISSUE_A((K0) + 64, aF);                                               \
    CVTB(SET, bN);                                                        \
    ISSUE_B(SET, (K0) + 96);                                              \
    COMPUTE(aC, bC);                                                      \
    PHASE_BAR(18);                                                        \
    int tmp_ = aC; aC = aN; aN = aF; aF = tmp_;                           \
    tmp_ = bC; bC = bN; bN = tmp_;                                        \
  } while (0)

// ---------------- fused MFMA GEMM pair, 2-step-cover pipeline ----------------
// DOWN=0: shared-gu (0..703) + expert-gu (704..2111), K=2048, nt=64
// DOWN=1: shared-down splitK4 (0..511) + expert-down (512..1535), nt=44
template <int DOWN>
__global__ void __launch_bounds__(256, 4) k_mm(
    const unsigned short* __restrict__ A_sh, const unsigned short* __restrict__ A_ex,
    const float* __restrict__ B_sh, const float* __restrict__ B_ex,
    unsigned short* __restrict__ act_sh, unsigned short* __restrict__ act_ex,
    float* __restrict__ out,
    const int* __restrict__ counts, const int* __restrict__ tlist,
    const float* __restrict__ wlist, const float* __restrict__ gate_sig) {
  const int tid = threadIdx.x;
  const int lane = tid & 63;
  const int wid = tid >> 6;
  const int wm = wid >> 1, wn = wid & 1;

  constexpr int SHBLK = DOWN ? 512 : 704;
  const int b0 = blockIdx.x;
  const bool ex = b0 >= SHBLK;
  const int b = ex ? b0 - SHBLK : b0;
  const int xcd = b & 7;
  const int j = b >> 3;
  const int mtile = j & 7;
  int e = 0, ntile = 0, z = 0;
  if constexpr (!DOWN) {
    if (!ex) ntile = xcd * 11 + (j >> 3);
    else { int p = xcd * 22 + (j >> 3); e = p & 7; ntile = p >> 3; }
  } else {
    if (!ex) { int p = xcd * 8 + (j >> 3); ntile = p >> 2; z = p & 3; }
    else { int p = xcd * 16 + (j >> 3); e = p & 7; ntile = p >> 3; }
  }

  int lda, ldb, IK = 0, kbeg = 0, count = T_TOK;
  const unsigned short* A;
  const float* B0; const float* B1;
  const int* tlA = nullptr;   // A-row gather (gu-expert ONLY)
  const int* tlO = nullptr;   // output token scatter (down-expert ONLY)
  const float* wl = nullptr;
  unsigned short* actout = nullptr;

  if constexpr (!DOWN) {
    lda = H_DIM;
    if (!ex) {
      ldb = 2 * ISD; IK = ISD; A = A_sh; actout = act_sh;
      B0 = B_sh + ntile * 64; B1 = B_sh + ISD + ntile * 64;
    } else {
      count = counts[e];
      if (mtile * 128 >= count) return;
      ldb = 2 * IED; IK = IED; A = A_sh;
      const float* Bw = B_ex + (size_t)e * H_DIM * (2 * IED);
      B0 = Bw + ntile * 64; B1 = Bw + IED + ntile * 64;
      tlA = tlist + e * T_TOK; wl = wlist + e * T_TOK;
      actout = act_ex + (size_t)e * T_TOK * IED;
    }
  } else {
    ldb = H_DIM;
    if (!ex) {
      lda = ISD; kbeg = z * 1408; A = A_sh;
      B0 = B_sh + ntile * 128; B1 = B0 + 64;
    } else {
      count = counts[e];
      if (mtile * 128 >= count) return;
      lda = IED; A = A_ex + (size_t)e * T_TOK * IED;  // rows indexed by SLOT
      B0 = B_ex + (size_t)e * IED * H_DIM + ntile * 128; B1 = B0 + 64;
      tlO = tlist + e * T_TOK;
    }
  }
  const int nt = DOWN ? 44 : 64;
  const int kend4 = kbeg + (nt - 4) * 32;  // start of epilogue K

  __shared__ unsigned short a_lds[3 * 4096];  // 3 bufs x [128 rows][32]
  __shared__ unsigned short b_lds[2 * 4096];  // 2 bufs x [128 prows][32]

  // A: global_load_lds, pre-swizzled source chunk, linear LDS dest.
  const unsigned short* asrc[2];
  unsigned short* adst[2];
#pragma unroll
  for (int q = 0; q < 2; q++) {
    int row = wid * 32 + q * 16 + (lane >> 2);
    int rowg = mtile * 128 + row;
    int arow = rowg;
    if (tlA) arow = tlA[rowg];  // padding slots hold 0 (memset)
    asrc[q] = A + (size_t)arow * lda + (((lane & 3) ^ SWZ(row)) * 8);
    adst[q] = &a_lds[(wid * 32 + q * 16) * 32];
  }

  // B staging: half = tid>>7 picks B0/B1; 2 cols bn,bn+1; k-chunk kg.
  // LDS rows permuted by PERM so each write instruction mixes row parity.
  const int half = tid >> 7;
  const int bn = (tid & 31) * 2;
  const int kg = (tid >> 5) & 3;
  const int bks = kg * 8;
  const float* Bh = half ? B1 : B0;
  unsigned short* bwr[2];
#pragma unroll
  for (int jj = 0; jj < 2; jj++) {
    int nl = half * 64 + bn + jj;   // logical tile row
    int rp = PERM(nl);
    bwr[jj] = &b_lds[rp * 32 + ((kg ^ SWZ(rp)) * 8)];
  }

  const f32x4 fzero = {0.f, 0.f, 0.f, 0.f};
  f32x4 acc[4][4];
#pragma unroll
  for (int m = 0; m < 4; m++)
#pragma unroll
    for (int n = 0; n < 4; n++) acc[m][n] = fzero;

  float2 RBa[8], RBb[8];
  int aC = 0, aN = 4096, aF = 8192;
  int bC = 0, bN = 4096;

  // ---- prologue ----
  ISSUE_A(kbeg, 0);              // A(0)            [2]
  ISSUE_B(RBa, kbeg);            // B(0)            [8]
  ISSUE_A(kbeg + 32, 4096);      // A(1)            [2]
  ISSUE_B(RBb, kbeg + 32);       // B(1)            [8]
  CVTB(RBa, 0);                  // waits B(0) (drains A(0) too); writes b0
  ISSUE_B(RBa, kbeg + 64);       // B(2)            [8]
  __builtin_amdgcn_sched_barrier(0);
  asm volatile("s_waitcnt lgkmcnt(0)" ::: "memory");
  __builtin_amdgcn_s_barrier();
  __builtin_amdgcn_sched_barrier(0);
  // pending: A(1)[2], B(1)[8], B(2)[8]

  // main: steps u=0..nt-5 (even count). STEP(even)->RBb, STEP(odd)->RBa.
  for (int k0 = kbeg; k0 < kend4; k0 += 64) {
    STEP_FULL(RBb, k0);
    STEP_FULL(RBa, k0 + 32);
  }
  {
    const int k0 = kend4;  // u = nt-4
    STEP_FULL(RBb, k0);                      // full; barrier vmcnt(18)
    // u = nt-3: A(nt-1), CVT B(nt-2), no B-refill
    ISSUE_A(k0 + 96, aF);
    CVTB(RBa, bN);
    COMPUTE(aC, bC);
    PHASE_BAR(10);                           // drain A(nt-2)
    int tmp_ = aC; aC = aN; aN = aF; aF = tmp_;
    tmp_ = bC; bC = bN; bN = tmp_;
    // u = nt-2: CVT B(nt-1) only
    CVTB(RBb, bN);
    COMPUTE(aC, bC);
    PHASE_BAR(0);                            // drain A(nt-1)
    tmp_ = aC; aC = aN; aN = aF; aF = tmp_;
    tmp_ = bC; bC = bN; bN = tmp_;
    // u = nt-1: compute only
    COMPUTE(aC, bC);
  }

  if constexpr (!DOWN) {
#pragma unroll
    for (int m = 0; m < 4; m++) {
#pragma unroll
      for (int i = 0; i < 4; i++) {
        int rowslot = mtile * 128 + wm * 64 + m * 16 + (lane >> 4) * 4 + i;
        float rsc = 1.f;
        if (wl) rsc = wl[rowslot];  // padding slots: 0.0 (memset)
#pragma unroll
        for (int p = 0; p < 2; p++) {
          float g = acc[m][p][i];
          float u2 = acc[m][p + 2][i];
          float sv = g / (1.f + __expf(-g)) * u2 * rsc;
          int col = ntile * 64 + wn * 32 + p * 16 + (lane & 15);
          actout[(size_t)rowslot * IK + col] = f2bf(sv);
        }
      }
    }
  } else {
#pragma unroll
    for (int m = 0; m < 4; m++) {
#pragma unroll
      for (int i = 0; i < 4; i++) {
        int rowslot = mtile * 128 + wm * 64 + m * 16 + (lane >> 4) * 4 + i;
        int token = rowslot;
        if (tlO) token = tlO[rowslot];  // padding: token 0, acc==0
        float sc = ex ? 1.f : gate_sig[token];
        float* orow = out + (size_t)token * H_DIM + ntile * 128 + wn * 64 + (lane & 15);
#pragma unroll
        for (int nf = 0; nf < 4; nf++)
          atomicAdd(orow + nf * 16, acc[m][nf][i] * sc);
      }
    }
  }
}

extern "C" void kernel_launch(void* const* d_in, const int* in_sizes, int n_in,
                              void* d_out, int out_size, void* d_ws, size_t ws_size,
                              hipStream_t stream) {
  (void)in_sizes; (void)n_in; (void)out_size; (void)ws_size;
  const float* x    = (const float*)d_in[0];
  const float* wg   = (const float*)d_in[1];
  const float* wsg  = (const float*)d_in[2];
  const float* wsgu = (const float*)d_in[3];
  const float* wsd  = (const float*)d_in[4];
  const float* wegu = (const float*)d_in[5];
  const float* wed  = (const float*)d_in[6];
  float* out = (float*)d_out;

  char* ws = (char*)d_ws;
  unsigned short* xb   = (unsigned short*)ws;                                   // 4 MB
  unsigned short* acts = (unsigned short*)(ws + (4u << 20));                    // T*ISD bf16
  unsigned short* acte = (unsigned short*)(ws + (4u << 20) + 11534336u);        // E*T*IED bf16
  char* ctrl = ws + (4u << 20) + 11534336u + 23068672u;
  int* counts    = (int*)ctrl;
  int* tlist     = (int*)(ctrl + 256);
  float* wlist   = (float*)(ctrl + 256 + 32768);
  float* gate_sig = (float*)(ctrl + 256 + 65536);

  hipMemsetAsync(d_out, 0, (size_t)T_TOK * H_DIM * 4, stream);
  hipMemsetAsync(ctrl, 0, 256 + 65536, stream);

  k_router<<<dim3(256), dim3(256), 0, stream>>>(x, wg, wsg, xb, counts, tlist, wlist, gate_sig);
  k_mm<0><<<dim3(2112), dim3(256), 0, stream>>>(xb, xb, wsgu, wegu, acts, acte, nullptr,
                                                counts, tlist, wlist, gate_sig);
  k_mm<1><<<dim3(1536), dim3(256), 0, stream>>>(acts, acte, wsd, wed, nullptr, nullptr, out,
                                                counts, tlist, wlist, gate_sig);
}

// Round 10
// 472.029 us; speedup vs baseline: 2.2966x; 1.9096x over previous
//
#include <hip/hip_runtime.h>
#include <hip/hip_bf16.h>
#include <stdint.h>

#define T_TOK 1024
#define H_DIM 2048
#define NEXP 8
#define IED 1408
#define ISD 5632

typedef __attribute__((ext_vector_type(8))) short s16x8;
typedef __attribute__((ext_vector_type(8))) unsigned short u16x8;
typedef __attribute__((ext_vector_type(4))) float f32x4;

// 4-chunk swizzle, bank-quad balanced over 16-row period
#define SWZ(r) (((r) ^ ((r) >> 2)) & 3)

// HW bf16 convert (RNE, lowers to v_cvt_pk_bf16_f32)
__device__ __forceinline__ unsigned short f2bf(float f) {
  union { __hip_bfloat16 b; unsigned short u; } v;
  v.b = __float2bfloat16(f);
  return v.u;
}

__device__ __forceinline__ void gload16(const void* g, void* l) {
  __builtin_amdgcn_global_load_lds(
      (const __attribute__((address_space(1))) unsigned int*)g,
      (__attribute__((address_space(3))) unsigned int*)l, 16, 0, 0);
}

// ---------------- router + x->bf16 convert (fused) ----------------
extern "C" __global__ void __launch_bounds__(256) k_router(
    const float* __restrict__ x, const float* __restrict__ wg,
    const float* __restrict__ wsg, unsigned short* __restrict__ xb,
    int* __restrict__ counts, int* __restrict__ tlist,
    float* __restrict__ wlist, float* __restrict__ gate_sig) {
  const int tid = threadIdx.x;
  const int bb = blockIdx.x;
#pragma unroll
  for (int it = 0; it < 8; it++) {
    int i = bb * 8192 + it * 1024 + tid * 4;
    float4 v = *(const float4*)(x + i);
    ushort4 o;
    o.x = f2bf(v.x); o.y = f2bf(v.y); o.z = f2bf(v.z); o.w = f2bf(v.w);
    *(ushort4*)(xb + i) = o;
  }
  const int lane = tid & 63;
  const int t = bb * 4 + (tid >> 6);
  const float* xr = x + (size_t)t * H_DIM;
  float acc[8];
#pragma unroll
  for (int e = 0; e < 8; e++) acc[e] = 0.f;
  float sg = 0.f;
  for (int h = lane; h < H_DIM; h += 64) {
    float xv = xr[h];
    float4 w0 = *(const float4*)(wg + h * 8);
    float4 w1 = *(const float4*)(wg + h * 8 + 4);
    acc[0] += xv * w0.x; acc[1] += xv * w0.y; acc[2] += xv * w0.z; acc[3] += xv * w0.w;
    acc[4] += xv * w1.x; acc[5] += xv * w1.y; acc[6] += xv * w1.z; acc[7] += xv * w1.w;
    sg += xv * wsg[h];
  }
#pragma unroll
  for (int d = 32; d >= 1; d >>= 1) {
#pragma unroll
    for (int e = 0; e < 8; e++) acc[e] += __shfl_xor(acc[e], d, 64);
    sg += __shfl_xor(sg, d, 64);
  }
  if (lane == 0) {
    float m = acc[0];
#pragma unroll
    for (int e = 1; e < 8; e++) m = fmaxf(m, acc[e]);
    float p[8], s = 0.f;
#pragma unroll
    for (int e = 0; e < 8; e++) { p[e] = __expf(acc[e] - m); s += p[e]; }
    float inv = 1.f / s;
    bool used[8];
#pragma unroll
    for (int e = 0; e < 8; e++) used[e] = false;
    for (int j = 0; j < 4; j++) {
      int be = 0; float bv = -1e30f;
#pragma unroll
      for (int e = 0; e < 8; e++)
        if (!used[e] && acc[e] > bv) { bv = acc[e]; be = e; }
      used[be] = true;
      int slot = atomicAdd(counts + be, 1);
      tlist[be * T_TOK + slot] = t;
      wlist[be * T_TOK + slot] = p[be] * inv;
    }
    gate_sig[t] = 1.f / (1.f + __expf(-sg));
  }
}

// ---------------- staging / compute macros (BK=32, 512 threads) ----------------
// A: 1 gload16/thread. row = tid>>2, chunkpos = tid&3, source chunk pre-swizzled.
#define ISSUE_A(kk, AOFF)                                                 \
  do {                                                                    \
    gload16(asrc + (kk), adst + (AOFF));                                  \
    __builtin_amdgcn_sched_barrier(0);                                    \
  } while (0)

// B: 8 dword loads/thread. col bnn = tid&127 (wave = 64 consecutive cols),
// k = kk + bc*8 + j. Coalesced 256B/wave/instruction.
#define ISSUE_B(kk)                                                       \
  do {                                                                    \
    _Pragma("unroll") for (int j = 0; j < 8; j++)                         \
        RB[j] = Bh[(size_t)((kk) + bc * 8 + j) * (size_t)ldb];            \
    __builtin_amdgcn_sched_barrier(0);                                    \
  } while (0)

// convert 8 fp32 -> one b128 LDS write at [bnn][chunk bc^SWZ(bnn)]
#define CVTB(BOFF)                                                        \
  do {                                                                    \
    u16x8 pk;                                                             \
    _Pragma("unroll") for (int j = 0; j < 8; j++) pk[j] = f2bf(RB[j]);    \
    *(u16x8*)(bwr + (BOFF)) = pk;                                         \
  } while (0)

// 8 MFMAs/wave: 4 m-frags x 2 n-frags (nf*64 = g/u half or down col-block)
#define COMPUTE(AOFF, BOFF)                                               \
  do {                                                                    \
    const unsigned short* ab = a_lds + (AOFF);                            \
    const unsigned short* bb2 = b_lds + (BOFF);                           \
    __builtin_amdgcn_s_setprio(1);                                        \
    {                                                                     \
      const int kc = lane >> 4;                                           \
      s16x8 afr[4];                                                       \
      _Pragma("unroll") for (int m = 0; m < 4; m++) {                     \
        int r = wm * 64 + m * 16 + (lane & 15);                           \
        afr[m] = *(const s16x8*)&ab[r * 32 + ((kc ^ SWZ(r)) * 8)];        \
      }                                                                   \
      _Pragma("unroll") for (int nf = 0; nf < 2; nf++) {                  \
        int rb_ = wn * 16 + nf * 64 + (lane & 15);                        \
        s16x8 bfr = *(const s16x8*)&bb2[rb_ * 32 + ((kc ^ SWZ(rb_)) * 8)]; \
        _Pragma("unroll") for (int m = 0; m < 4; m++)                     \
            acc[m][nf] = __builtin_amdgcn_mfma_f32_16x16x32_bf16(         \
                afr[m], bfr, acc[m][nf], 0, 0, 0);                        \
      }                                                                   \
    }                                                                     \
    __builtin_amdgcn_s_setprio(0);                                        \
  } while (0)

// ---------------- fused MFMA GEMM pair, 8-wave blocks ----------------
// DOWN=0: shared-gu (0..703) + expert-gu (704..2111), nt=64
// DOWN=1: shared-down splitK4 (0..511) + expert-down (512..1535), nt=44
template <int DOWN>
__global__ void k_mm(
    const unsigned short* __restrict__ A_sh, const unsigned short* __restrict__ A_ex,
    const float* __restrict__ B_sh, const float* __restrict__ B_ex,
    unsigned short* __restrict__ act_sh, unsigned short* __restrict__ act_ex,
    float* __restrict__ out,
    const int* __restrict__ counts, const int* __restrict__ tlist,
    const float* __restrict__ wlist, const float* __restrict__ gate_sig) {
  const int tid = threadIdx.x;
  const int lane = tid & 63;
  const int wid = tid >> 6;
  const int wm = wid >> 2, wn = wid & 3;  // 8 waves: 2 row-halves x 4 col-quarters

  constexpr int SHBLK = DOWN ? 512 : 704;
  const int b0 = blockIdx.x;
  const bool ex = b0 >= SHBLK;
  const int b = ex ? b0 - SHBLK : b0;
  const int xcd = b & 7;
  const int j = b >> 3;
  const int mtile = j & 7;
  int e = 0, ntile = 0, z = 0;
  if constexpr (!DOWN) {
    if (!ex) ntile = xcd * 11 + (j >> 3);
    else { int p = xcd * 22 + (j >> 3); e = p & 7; ntile = p >> 3; }
  } else {
    if (!ex) { int p = xcd * 8 + (j >> 3); ntile = p >> 2; z = p & 3; }
    else { int p = xcd * 16 + (j >> 3); e = p & 7; ntile = p >> 3; }
  }

  int lda, ldb, IK = 0, kbeg = 0, count = T_TOK, nt;
  const unsigned short* A;
  const float* Bb0; const float* Bb1;
  const int* tlA = nullptr;   // A-row gather (gu-expert ONLY)
  const int* tlO = nullptr;   // output token scatter (down-expert ONLY)
  const float* wl = nullptr;
  unsigned short* actout = nullptr;

  if constexpr (!DOWN) {
    lda = H_DIM; nt = 64;
    if (!ex) {
      ldb = 2 * ISD; IK = ISD; A = A_sh; actout = act_sh;
      Bb0 = B_sh + ntile * 64; Bb1 = B_sh + ISD + ntile * 64;
    } else {
      count = counts[e];
      if (mtile * 128 >= count) return;
      ldb = 2 * IED; IK = IED; A = A_sh;
      const float* Bw = B_ex + (size_t)e * H_DIM * (2 * IED);
      Bb0 = Bw + ntile * 64; Bb1 = Bw + IED + ntile * 64;
      tlA = tlist + e * T_TOK; wl = wlist + e * T_TOK;
      actout = act_ex + (size_t)e * T_TOK * IED;
    }
  } else {
    ldb = H_DIM; nt = 44;
    if (!ex) {
      lda = ISD; kbeg = z * 1408; A = A_sh;   // splitK4: 4 x 1408 = 5632 = ISD
      Bb0 = B_sh + ntile * 128; Bb1 = Bb0;
    } else {
      count = counts[e];
      if (mtile * 128 >= count) return;
      lda = IED; A = A_ex + (size_t)e * T_TOK * IED;  // rows by SLOT
      Bb0 = B_ex + (size_t)e * IED * H_DIM + ntile * 128; Bb1 = Bb0;
      tlO = tlist + e * T_TOK;
    }
  }

  __shared__ unsigned short a_lds[2 * 4096];  // 2 bufs x [128 rows][32]
  __shared__ unsigned short b_lds[2 * 4096];  // 2 bufs x [128 ncols][32]

  // A staging: row = tid>>2, chunkpos = tid&3; source chunk = pos ^ SWZ(row).
  const unsigned short* asrc;
  unsigned short* adst;
  {
    int row = tid >> 2;
    int rowg = mtile * 128 + row;
    int arow = rowg;
    if (tlA) arow = tlA[rowg];  // padding slots hold 0 (memset)
    asrc = A + (size_t)arow * lda + (((tid & 3) ^ SWZ(row)) * 8);
    adst = &a_lds[(tid >> 6) * 512];  // wave-uniform base; HW adds lane*16B
  }

  // B staging: col bnn = tid&127, k-chunk bc = tid>>7 (8 k's each).
  const int bnn = tid & 127;
  const int bc = tid >> 7;
  const float* Bh;
  if constexpr (!DOWN) Bh = (bnn < 64) ? (Bb0 + bnn) : (Bb1 + (bnn - 64));
  else Bh = Bb0 + bnn;
  unsigned short* bwr = &b_lds[bnn * 32 + ((bc ^ SWZ(bnn)) * 8)];

  const f32x4 fzero = {0.f, 0.f, 0.f, 0.f};
  f32x4 acc[4][2];
#pragma unroll
  for (int m = 0; m < 4; m++)
#pragma unroll
    for (int n = 0; n < 2; n++) acc[m][n] = fzero;

  float RB[8];

  // ---- prologue ----
  ISSUE_B(kbeg);           // B(0)  [8]
  ISSUE_A(kbeg, 0);        // A(0)  [1]
  CVTB(0);                 // waits B(0) regs (A(0) newer, stays)
  ISSUE_B(kbeg + 32);      // B(1)  [8]
  __builtin_amdgcn_sched_barrier(0);
  asm volatile("s_waitcnt vmcnt(8)" ::: "memory");   // drain A(0); B(1) in flight
  asm volatile("s_waitcnt lgkmcnt(0)" ::: "memory");
  __builtin_amdgcn_s_barrier();
  __builtin_amdgcn_sched_barrier(0);

  for (int u = 0; u < nt; ++u) {
    const int cur = (u & 1) * 4096;
    const int nxt = cur ^ 4096;
    const int k0 = kbeg + u * 32;
    const bool haveN1 = (u + 1 < nt);
    const bool haveN2 = (u + 2 < nt);
    if (haveN1) {
      ISSUE_A(k0 + 32, nxt);           // A(u+1) -> nxt  [1]
      CVTB(nxt);                       // B(u+1) regs -> nxt (compiler-counted wait)
      if (haveN2) ISSUE_B(k0 + 64);    // B(u+2) -> regs [8]
    }
    COMPUTE(cur, cur);
    if (haveN1) {
      __builtin_amdgcn_sched_barrier(0);
      if (haveN2)
        asm volatile("s_waitcnt vmcnt(8)" ::: "memory");  // drain A(u+1); keep B(u+2)
      else
        asm volatile("s_waitcnt vmcnt(0)" ::: "memory");
      asm volatile("s_waitcnt lgkmcnt(0)" ::: "memory");
      __builtin_amdgcn_s_barrier();
      __builtin_amdgcn_sched_barrier(0);
    }
  }

  if constexpr (!DOWN) {
#pragma unroll
    for (int m = 0; m < 4; m++) {
#pragma unroll
      for (int i = 0; i < 4; i++) {
        int rowslot = mtile * 128 + wm * 64 + m * 16 + (lane >> 4) * 4 + i;
        float rsc = 1.f;
        if (wl) rsc = wl[rowslot];  // padding slots: 0.0 (memset)
        float g = acc[m][0][i];
        float u2 = acc[m][1][i];
        float sv = g / (1.f + __expf(-g)) * u2 * rsc;
        int col = ntile * 64 + wn * 16 + (lane & 15);
        actout[(size_t)rowslot * IK + col] = f2bf(sv);
      }
    }
  } else {
#pragma unroll
    for (int m = 0; m < 4; m++) {
#pragma unroll
      for (int i = 0; i < 4; i++) {
        int rowslot = mtile * 128 + wm * 64 + m * 16 + (lane >> 4) * 4 + i;
        int token = rowslot;
        if (tlO) token = tlO[rowslot];  // padding: token 0, acc==0
        float sc = ex ? 1.f : gate_sig[token];
        float* orow = out + (size_t)token * H_DIM + ntile * 128 + wn * 16 + (lane & 15);
#pragma unroll
        for (int nf = 0; nf < 2; nf++)
          atomicAdd(orow + nf * 64, acc[m][nf][i] * sc);
      }
    }
  }
}

extern "C" void kernel_launch(void* const* d_in, const int* in_sizes, int n_in,
                              void* d_out, int out_size, void* d_ws, size_t ws_size,
                              hipStream_t stream) {
  (void)in_sizes; (void)n_in; (void)out_size; (void)ws_size;
  const float* x    = (const float*)d_in[0];
  const float* wg   = (const float*)d_in[1];
  const float* wsg  = (const float*)d_in[2];
  const float* wsgu = (const float*)d_in[3];
  const float* wsd  = (const float*)d_in[4];
  const float* wegu = (const float*)d_in[5];
  const float* wed  = (const float*)d_in[6];
  float* out = (float*)d_out;

  char* ws = (char*)d_ws;
  unsigned short* xb   = (unsigned short*)ws;                                   // 4 MB
  unsigned short* acts = (unsigned short*)(ws + (4u << 20));                    // T*ISD bf16
  unsigned short* acte = (unsigned short*)(ws + (4u << 20) + 11534336u);        // E*T*IED bf16
  char* ctrl = ws + (4u << 20) + 11534336u + 23068672u;
  int* counts    = (int*)ctrl;
  int* tlist     = (int*)(ctrl + 256);
  float* wlist   = (float*)(ctrl + 256 + 32768);
  float* gate_sig = (float*)(ctrl + 256 + 65536);

  hipMemsetAsync(d_out, 0, (size_t)T_TOK * H_DIM * 4, stream);
  hipMemsetAsync(ctrl, 0, 256 + 65536, stream);

  k_router<<<dim3(256), dim3(256), 0, stream>>>(x, wg, wsg, xb, counts, tlist, wlist, gate_sig);
  k_mm<0><<<dim3(2112), dim3(512), 0, stream>>>(xb, xb, wsgu, wegu, acts, acte, nullptr,
                                                counts, tlist, wlist, gate_sig);
  k_mm<1><<<dim3(1536), dim3(512), 0, stream>>>(acts, acte, wsd, wed, nullptr, nullptr, out,
                                                counts, tlist, wlist, gate_sig);
}